// Round 10
// baseline (199.002 us; speedup 1.0000x reference)
//
#include <hip/hip_runtime.h>

// out = L@(X@W1 + X^2@W2) + X@W1 + b1 + b2
// Y (bf16, ws) = X@W1 + X^2@W2 ; Z = X@W1 + b1 + b2.
// Pipeline (r7 structure, unfused -- fusion measured neutral r8/r9):
//   node_transform (MFMA 16x16x32, zero LDS; folds cursor/ghist init) ->
//   bin_scatter (LDS chunk-sort, single-atomic-pass, register-carried
//   edges; ALSO counts ghist[row] via no-return global atomics) ->
//   bucket_gather_half (2 blocks/bucket row halves; ghist-precomputed
//   offsets: 1-wave scan, ONE packed pass sorting only own-half edges,
//   uint2 = 4x bf16 gather loads, register accumulation, float4 out RMW)
//   -> overflow_scatter (empty in practice).
//
// MEASURED LESSONS:
//  r3/r4: LDS fp32 atomicAdd (plain AND unsafeAtomicAdd -- identical
//    codegen) ~139 cyc/op fully serialized on gfx950. No LDS fp atomics
//    in hot accumulation loops; counting-sort + register acc wins 13x.
//  r6: per-edge global atomic-RETURN allocation on 784 hot lines = 83us
//    (latency-serialized) + 67MB write amplification. LDS chunk-sort wins.
//    (No-return atomics spread over 100K addresses are fine -- used here.)
//  r8/r9: NT+scatter fusion (contiguous or Bresenham-interleaved) is
//    NEUTRAL-to-negative vs r7 serial launches; 512-thread 1-block/bucket
//    gather slower than 2x256. r7 unfused = 160.8us baseline.

#define ROWS_PER_BUCKET 128
#define ROW_SHIFT 7
#define NBUCK_PAD 784        // 196*4, covers nbuck=782
#define SCAN_T 196
#define CAP 2048             // per-bucket fixed capacity
#define CHUNK 4096           // edges per bin_scatter block
#define EPT 16               // CHUNK / 256 edges per thread
#define COL_BITS 17
#define COL_MASK 0x1FFFF
#define OVF_CAP 65536

typedef __attribute__((ext_vector_type(8))) short bf16x8;
typedef __attribute__((ext_vector_type(4))) float f32x4;

__device__ __forceinline__ unsigned short f2bf(float x) {
    unsigned u = __float_as_uint(x);
    unsigned r = (u + 0x7FFFu + ((u >> 16) & 1u)) >> 16;   // RNE
    return (unsigned short)r;
}
__device__ __forceinline__ float bf2f(unsigned short h) {
    return __uint_as_float(((unsigned)h) << 16);
}

// MFMA node transform: block = 256 threads = 4 waves, 128 rows/block.
// Wave w: rows base+w*32 .. +31. Frags: A row = lane&15, k = 8*(lane>>4)+j;
// B col = lane&15, same k; D row = 4*(lane>>4)+i, col = lane&15.
// Also initializes gcursor/ovf_count and zeroes ghist (all dead until
// bin_scatter launches).
__global__ __launch_bounds__(256) void node_transform(
    const float* __restrict__ X, const float* __restrict__ W1,
    const float* __restrict__ b1, const float* __restrict__ W2,
    const float* __restrict__ b2, unsigned short* __restrict__ Yb,
    float* __restrict__ Z, int n_nodes,
    int* __restrict__ gcursor, int* __restrict__ ovf_count,
    int* __restrict__ ghist)
{
    const int tid = threadIdx.x;

    // folded cursor/ghist init
    if (gcursor) {
        int gi = blockIdx.x * 256 + tid;
        if (gi < NBUCK_PAD) gcursor[gi] = gi * CAP;
        if (gi == 0) *ovf_count = 0;
        for (int k = gi; k < NBUCK_PAD * ROWS_PER_BUCKET; k += gridDim.x * 256)
            ghist[k] = 0;
    }

    const int lane = tid & 63;
    const int wave = tid >> 6;          // 0..3
    const int lg = lane >> 4;           // 0..3
    const int lr = lane & 15;

    const int base = blockIdx.x * 128 + wave * 32;

    // ---- B fragments in registers: [mat][ks][cf] ----
    bf16x8 bw1[2][4];
    bf16x8 bw2[2][4];
#pragma unroll
    for (int ks = 0; ks < 2; ++ks) {
#pragma unroll
        for (int cf = 0; cf < 4; ++cf) {
            const int col = cf * 16 + lr;
            const int k0 = ks * 32 + lg * 8;
            bf16x8 t1, t2;
#pragma unroll
            for (int j = 0; j < 8; ++j) {
                t1[j] = (short)f2bf(W1[(k0 + j) * 64 + col]);
                t2[j] = (short)f2bf(W2[(k0 + j) * 64 + col]);
            }
            bw1[ks][cf] = t1;
            bw2[ks][cf] = t2;
        }
    }

    f32x4 acc1[2][4];
    f32x4 acc2[2][4];
#pragma unroll
    for (int rf = 0; rf < 2; ++rf)
#pragma unroll
        for (int cf = 0; cf < 4; ++cf) {
            acc1[rf][cf] = (f32x4){0.f, 0.f, 0.f, 0.f};
            acc2[rf][cf] = (f32x4){0.f, 0.f, 0.f, 0.f};
        }

    // ---- main: load A (X rows, coalesced 32B/lane), square, MFMA ----
#pragma unroll
    for (int rf = 0; rf < 2; ++rf) {
        const int row = base + rf * 16 + lr;
        const bool rok = row < n_nodes;
        const float* xp = X + (size_t)row * 64 + lg * 8;
#pragma unroll
        for (int ks = 0; ks < 2; ++ks) {
            float xv[8];
            if (rok) {
                float4 v0 = *(const float4*)(xp + ks * 32);
                float4 v1 = *(const float4*)(xp + ks * 32 + 4);
                xv[0] = v0.x; xv[1] = v0.y; xv[2] = v0.z; xv[3] = v0.w;
                xv[4] = v1.x; xv[5] = v1.y; xv[6] = v1.z; xv[7] = v1.w;
            } else {
#pragma unroll
                for (int j = 0; j < 8; ++j) xv[j] = 0.f;
            }
            bf16x8 a, q;
#pragma unroll
            for (int j = 0; j < 8; ++j) {
                a[j] = (short)f2bf(xv[j]);
                float s = xv[j] * xv[j];
                q[j] = (short)f2bf(s);
            }
#pragma unroll
            for (int cf = 0; cf < 4; ++cf) {
                acc1[rf][cf] = __builtin_amdgcn_mfma_f32_16x16x32_bf16(
                    a, bw1[ks][cf], acc1[rf][cf], 0, 0, 0);
                acc2[rf][cf] = __builtin_amdgcn_mfma_f32_16x16x32_bf16(
                    q, bw2[ks][cf], acc2[rf][cf], 0, 0, 0);
            }
        }
    }

    // ---- epilogue ----
    float bsv[4];
#pragma unroll
    for (int cf = 0; cf < 4; ++cf)
        bsv[cf] = b1[cf * 16 + lr] + b2[cf * 16 + lr];

#pragma unroll
    for (int rf = 0; rf < 2; ++rf) {
#pragma unroll
        for (int i = 0; i < 4; ++i) {
            const int row = base + rf * 16 + lg * 4 + i;
            if (row < n_nodes) {
#pragma unroll
                for (int cf = 0; cf < 4; ++cf) {
                    const float v1 = acc1[rf][cf][i];
                    const float y = v1 + acc2[rf][cf][i];
                    const float z = v1 + bsv[cf];
                    Yb[(size_t)row * 64 + cf * 16 + lr] = f2bf(y);
                    Z[(size_t)row * 64 + cf * 16 + lr] = z;
                }
            }
        }
    }
}

// ---------------- fixed-capacity bucket build ----------------

// LDS-staged binned scatter, single-atomic-pass variant (r7) + ghist:
//  pass 1: read each edge ONCE; LDS histogram atomic's return value is the
//          in-bucket position; edge data stays in registers; ALSO bump
//          ghist[row] (global no-return atomic, 100K spread addresses).
//  scan:   per-wave __shfl_up inclusive scan + 4-entry cross-wave fixup.
//  stage:  int2 LDS write at lstart[b]+p, no second atomic.
//  out:    i-ordered walk -> coalesced runs into packed[] per bucket.
__global__ __launch_bounds__(256) void bin_scatter(
    const int* __restrict__ rows, const int* __restrict__ cols,
    const float* __restrict__ vals, int* __restrict__ gcursor,
    int2* __restrict__ packed, int* __restrict__ ovf_count,
    int4* __restrict__ ovf, int* __restrict__ ghist, int n_edges) {
    __shared__ int lcount[NBUCK_PAD];              // 3.1 KB
    __shared__ int lstart[NBUCK_PAD];              // 3.1 KB
    __shared__ int gbase[NBUCK_PAD];               // 3.1 KB
    __shared__ int2 sxy[CHUNK];                    // 32 KB
    __shared__ unsigned short sbk[CHUNK];          // 8 KB
    __shared__ int wsum[4];

    int tid = threadIdx.x;
    int eb0 = blockIdx.x * CHUNK;
    int cnt = min(CHUNK, n_edges - eb0);

    for (int k = tid; k < NBUCK_PAD; k += 256) lcount[k] = 0;
    __syncthreads();

    // pass 1: single read + histogram with position capture + ghist count
    int eb_[EPT], ep_[EPT], ex_[EPT], ey_[EPT];
#pragma unroll
    for (int t = 0; t < EPT; ++t) {
        int i = tid + 256 * t;
        if (i < cnt) {
            int r = rows[eb0 + i];
            int b = r >> ROW_SHIFT;
            eb_[t] = b;
            ep_[t] = atomicAdd(&lcount[b], 1);
            atomicAdd(&ghist[r], 1);               // no-return, fire-and-forget
            ex_[t] = ((r & (ROWS_PER_BUCKET - 1)) << COL_BITS) | cols[eb0 + i];
            ey_[t] = __float_as_int(vals[eb0 + i]);
        } else {
            eb_[t] = -1; ep_[t] = 0; ex_[t] = 0; ey_[t] = 0;
        }
    }
    __syncthreads();

    // exclusive scan of lcount: thread t<SCAN_T owns buckets 4t..4t+3
    int c0 = 0, c1 = 0, c2 = 0, c3 = 0, psum = 0;
    if (tid < SCAN_T) {
        c0 = lcount[tid * 4 + 0]; c1 = lcount[tid * 4 + 1];
        c2 = lcount[tid * 4 + 2]; c3 = lcount[tid * 4 + 3];
        psum = c0 + c1 + c2 + c3;
    }
    const int lane = tid & 63;
    const int wv = tid >> 6;
    int incl = psum;
#pragma unroll
    for (int o = 1; o < 64; o <<= 1) {
        int n = __shfl_up(incl, o);
        if (lane >= o) incl += n;
    }
    if (lane == 63) wsum[wv] = incl;
    __syncthreads();
    int wpre = 0;
#pragma unroll
    for (int w = 0; w < 3; ++w)
        if (w < wv) wpre += wsum[w];
    int base0 = wpre + incl - psum;        // exclusive prefix of this thread
    if (tid < SCAN_T) {
        lstart[tid * 4 + 0] = base0;
        lstart[tid * 4 + 1] = base0 + c0;
        lstart[tid * 4 + 2] = base0 + c0 + c1;
        lstart[tid * 4 + 3] = base0 + c0 + c1 + c2;
    }
    __syncthreads();

    // reserve global space per bucket
    for (int k = tid; k < NBUCK_PAD; k += 256) {
        if (lcount[k] > 0) gbase[k] = atomicAdd(&gcursor[k], lcount[k]);
    }

    // stage from registers (no atomics)
#pragma unroll
    for (int t = 0; t < EPT; ++t) {
        if (eb_[t] >= 0) {
            int p = lstart[eb_[t]] + ep_[t];
            sxy[p] = make_int2(ex_[t], ey_[t]);
            sbk[p] = (unsigned short)eb_[t];
        }
    }
    __syncthreads();

    // output: i-ordered -> per-bucket coalesced runs
    for (int i = tid; i < cnt; i += 256) {
        int b = sbk[i];
        int2 a = sxy[i];
        int dest = gbase[b] + (i - lstart[b]);
        if (dest < (b + 1) * CAP) {
            packed[dest] = a;
        } else {
            int p = atomicAdd(ovf_count, 1);
            if (p < OVF_CAP)
                ovf[p] = make_int4(b * ROWS_PER_BUCKET + (a.x >> COL_BITS),
                                   a.x & COL_MASK, a.y, 0);
        }
    }
}

// 2 blocks per bucket (row halves). Row counts come precomputed in ghist:
// 1-wave shuffle scan over 64 counts -> offsets, then ONE pass over packed
// sorting only own-half edges into LDS (r7's version read packed 2x per
// block and histogrammed it again). Gather: 16 groups x 4 rows; 16 lanes
// per row, uint2 = 4 bf16 features/lane -> one full 128B Y row per load;
// register accumulation; float4 out RMW. ghist counts are upper bounds
// (include overflowed edges); actual placed count min(chc,CAP)-chs is used.
__global__ __launch_bounds__(256) void bucket_gather_half(
    const int* __restrict__ gcursor, const int2* __restrict__ packed,
    const int* __restrict__ ghist, const unsigned short* __restrict__ Yb,
    float* __restrict__ out, int n_nodes) {
    __shared__ int2 sxy[CAP];                      // 16 KB, sorted by row
    __shared__ int chs[64];
    __shared__ int chc[64];

    int tid = threadIdx.x;
    int bucket = blockIdx.x >> 1;
    int half = blockIdx.x & 1;
    int rhalf = half * 64;
    int fquad = tid & 15;                // features 4*fquad .. 4*fquad+3
    int grp = tid >> 4;                  // 0..15 row-groups
    int s = bucket * CAP;
    int e = min(gcursor[bucket], s + CAP);
    int cnt = e - s;
    int row0 = bucket * ROWS_PER_BUCKET;
    const uint2* __restrict__ Y64 = (const uint2*)Yb;   // row = 16 uint2

    // offsets for OUR half's 64 rows: 1-wave shuffle scan
    if (tid < 64) {
        int h = ghist[row0 + rhalf + tid];
        int incl = h;
#pragma unroll
        for (int o = 1; o < 64; o <<= 1) {
            int n = __shfl_up(incl, o);
            if (tid >= o) incl += n;
        }
        chs[tid] = incl - h;
        chc[tid] = incl - h;
    }
    __syncthreads();

    // single pass: sort own-half edges into LDS (packed is L2-hot)
    for (int i = tid; i < cnt; i += 256) {
        int2 a = packed[s + i];
        int lr = a.x >> COL_BITS;
        if ((lr >> 6) == half) {
            int p = atomicAdd(&chc[lr & 63], 1);
            if (p < CAP) {
                sxy[p] = a;
            } else {
                // pathological spill (ghist offsets exceeded CAP): direct
                // atomic accumulate; never executes in practice.
                int node = row0 + lr;
                int c = a.x & COL_MASK;
                float v = __int_as_float(a.y);
                if (node < n_nodes)
                    for (int f = 0; f < 64; ++f)
                        atomicAdd(&out[(size_t)node * 64 + f],
                                  v * bf2f(Yb[(size_t)c * 64 + f]));
            }
        }
    }
    __syncthreads();

    // gather: 16 groups x 4 rows; 16 lanes per row, 4 features/lane
    for (int rr = 0; rr < 4; ++rr) {
        int lr = grp * 4 + rr;           // 0..63 local row in half
        int node = row0 + rhalf + lr;
        int rs = chs[lr];
        int re = min(chc[lr], CAP);
        int rc = re - rs;
        if (rc <= 0 || node >= n_nodes) continue;
        float a0 = 0.f, a1 = 0.f, a2 = 0.f, a3 = 0.f;
        int j = 0;
        for (; j + 4 <= rc; j += 4) {
            int2 e0 = sxy[rs + j + 0], e1 = sxy[rs + j + 1];
            int2 e2 = sxy[rs + j + 2], e3 = sxy[rs + j + 3];
            uint2 u0 = Y64[(size_t)(e0.x & COL_MASK) * 16 + fquad];
            uint2 u1 = Y64[(size_t)(e1.x & COL_MASK) * 16 + fquad];
            uint2 u2 = Y64[(size_t)(e2.x & COL_MASK) * 16 + fquad];
            uint2 u3 = Y64[(size_t)(e3.x & COL_MASK) * 16 + fquad];
            float v0 = __int_as_float(e0.y), v1 = __int_as_float(e1.y);
            float v2 = __int_as_float(e2.y), v3 = __int_as_float(e3.y);
            a0 = fmaf(v0, __uint_as_float(u0.x << 16), a0);
            a1 = fmaf(v0, __uint_as_float(u0.x & 0xFFFF0000u), a1);
            a2 = fmaf(v0, __uint_as_float(u0.y << 16), a2);
            a3 = fmaf(v0, __uint_as_float(u0.y & 0xFFFF0000u), a3);
            a0 = fmaf(v1, __uint_as_float(u1.x << 16), a0);
            a1 = fmaf(v1, __uint_as_float(u1.x & 0xFFFF0000u), a1);
            a2 = fmaf(v1, __uint_as_float(u1.y << 16), a2);
            a3 = fmaf(v1, __uint_as_float(u1.y & 0xFFFF0000u), a3);
            a0 = fmaf(v2, __uint_as_float(u2.x << 16), a0);
            a1 = fmaf(v2, __uint_as_float(u2.x & 0xFFFF0000u), a1);
            a2 = fmaf(v2, __uint_as_float(u2.y << 16), a2);
            a3 = fmaf(v2, __uint_as_float(u2.y & 0xFFFF0000u), a3);
            a0 = fmaf(v3, __uint_as_float(u3.x << 16), a0);
            a1 = fmaf(v3, __uint_as_float(u3.x & 0xFFFF0000u), a1);
            a2 = fmaf(v3, __uint_as_float(u3.y << 16), a2);
            a3 = fmaf(v3, __uint_as_float(u3.y & 0xFFFF0000u), a3);
        }
        for (; j < rc; ++j) {
            int2 e0 = sxy[rs + j];
            uint2 u0 = Y64[(size_t)(e0.x & COL_MASK) * 16 + fquad];
            float v0 = __int_as_float(e0.y);
            a0 = fmaf(v0, __uint_as_float(u0.x << 16), a0);
            a1 = fmaf(v0, __uint_as_float(u0.x & 0xFFFF0000u), a1);
            a2 = fmaf(v0, __uint_as_float(u0.y << 16), a2);
            a3 = fmaf(v0, __uint_as_float(u0.y & 0xFFFF0000u), a3);
        }
        float4* op = (float4*)(out + (size_t)node * 64 + fquad * 4);
        float4 o = *op;
        o.x += a0; o.y += a1; o.z += a2; o.w += a3;
        *op = o;                                 // out holds Z
    }
}

// drains the (normally empty) overflow list with global atomics
__global__ __launch_bounds__(256) void overflow_scatter(
    const int* __restrict__ ovf_count, const int4* __restrict__ ovf,
    const unsigned short* __restrict__ Yb, float* __restrict__ out) {
    int cnt = min(*ovf_count, OVF_CAP);
    long long total = (long long)cnt * 64;
    for (long long i = blockIdx.x * 256 + threadIdx.x; i < total;
         i += (long long)gridDim.x * 256) {
        int e = (int)(i >> 6), f = (int)(i & 63);
        int4 a = ovf[e];
        atomicAdd(&out[(size_t)a.x * 64 + f],
                  __int_as_float(a.z) * bf2f(Yb[(size_t)a.y * 64 + f]));
    }
}

// ---------------- fallback (atomic path) ----------------

__global__ __launch_bounds__(256) void edge_scatter(
    const int* __restrict__ rows, const int* __restrict__ cols,
    const float* __restrict__ vals, const unsigned short* __restrict__ Yb,
    float* __restrict__ out, int n_edges)
{
    int t = blockIdx.x * 256 + threadIdx.x;
    int e = t >> 4;
    int f = (t & 15) << 2;
    if (e >= n_edges) return;
    int r = rows[e];
    int c = cols[e];
    float v = vals[e];
    const unsigned short* y = Yb + (size_t)c * 64 + f;
    float* o = out + (size_t)r * 64 + f;
    atomicAdd(o + 0, v * bf2f(y[0]));
    atomicAdd(o + 1, v * bf2f(y[1]));
    atomicAdd(o + 2, v * bf2f(y[2]));
    atomicAdd(o + 3, v * bf2f(y[3]));
}

extern "C" void kernel_launch(void* const* d_in, const int* in_sizes, int n_in,
                              void* d_out, int out_size, void* d_ws, size_t ws_size,
                              hipStream_t stream) {
    const int*   rows = (const int*)d_in[0];
    const int*   cols = (const int*)d_in[1];
    const float* vals = (const float*)d_in[2];
    const float* X    = (const float*)d_in[3];
    const float* W1   = (const float*)d_in[4];
    const float* b1   = (const float*)d_in[5];
    const float* W2   = (const float*)d_in[6];
    const float* b2   = (const float*)d_in[7];
    float* out = (float*)d_out;

    const int n_edges = in_sizes[0];
    const int n_nodes = in_sizes[3] / 64;
    const int nbuck = (n_nodes + ROWS_PER_BUCKET - 1) / ROWS_PER_BUCKET;

    char* ws = (char*)d_ws;
    size_t o_Yb     = 0;                                    // bf16 Y
    size_t o_packed = o_Yb + (size_t)n_nodes * 64 * 2;      // 16B-aligned (n*128)
    size_t o_ovf    = o_packed + (size_t)NBUCK_PAD * CAP * 8;
    size_t o_gcurs  = o_ovf + (size_t)OVF_CAP * 16;
    size_t o_ovfcnt = o_gcurs + NBUCK_PAD * 4;
    size_t o_ghist  = o_ovfcnt + 16;
    size_t need     = o_ghist + (size_t)NBUCK_PAD * ROWS_PER_BUCKET * 4;

    unsigned short* Yb = (unsigned short*)(ws + o_Yb);

    const bool fastpath =
        ws_size >= need && nbuck <= NBUCK_PAD && n_nodes <= (1 << COL_BITS);

    int2* packed  = (int2*)(ws + o_packed);
    int4* ovf     = (int4*)(ws + o_ovf);
    int*  gcursor = fastpath ? (int*)(ws + o_gcurs) : (int*)0;
    int*  ovfcnt  = (int*)(ws + o_ovfcnt);
    int*  ghist   = (int*)(ws + o_ghist);

    int nblocks = (n_nodes + 127) / 128;
    node_transform<<<nblocks, 256, 0, stream>>>(X, W1, b1, W2, b2, Yb, out,
                                                n_nodes, gcursor, ovfcnt, ghist);

    if (fastpath) {
        int eb = (n_edges + CHUNK - 1) / CHUNK;
        bin_scatter<<<eb, 256, 0, stream>>>(rows, cols, vals, gcursor, packed,
                                            ovfcnt, ovf, ghist, n_edges);
        bucket_gather_half<<<nbuck * 2, 256, 0, stream>>>(gcursor, packed, ghist,
                                                          Yb, out, n_nodes);
        overflow_scatter<<<128, 256, 0, stream>>>(ovfcnt, ovf, Yb, out);
    } else {
        long long threads = (long long)n_edges * 16;
        int eblocks = (int)((threads + 255) / 256);
        edge_scatter<<<eblocks, 256, 0, stream>>>(rows, cols, vals, Yb, out, n_edges);
    }
}

// Round 11
// 155.309 us; speedup vs baseline: 1.2813x; 1.2813x over previous
//
#include <hip/hip_runtime.h>

// out = L@(X@W1 + X^2@W2) + X@W1 + b1 + b2
// Y (bf16, ws) = X@W1 + X^2@W2 ; Z = X@W1 + b1 + b2.
// Pipeline (r7 structure, unfused):
//   node_transform (MFMA 16x16x32, zero LDS; folds cursor_init) ->
//   bin_scatter (LDS chunk-sort, single-atomic-pass, register-carried
//   edges; 512 threads for occupancy) -> bucket_gather_quads (2 blocks/
//   bucket row halves; in-LDS counting sort; uint2 = 4x bf16 gather loads;
//   register accumulation; float4 out RMW) -> overflow_scatter (empty).
//
// MEASURED LESSONS:
//  r3/r4: LDS fp32 atomicAdd (plain AND unsafeAtomicAdd -- identical
//    codegen) ~139 cyc/op fully serialized on gfx950. No LDS fp atomics
//    in hot accumulation; counting-sort + register acc wins 13x.
//  r6/r10: per-edge GLOBAL atomics lose BOTH ways -- hot-line atomic-rtn
//    (r6: 83us) AND spread no-return (r10: +25us on bin_scatter). Keep all
//    per-edge counting in LDS.
//  r8/r9: NT+scatter fusion (contiguous or interleaved) neutral-negative;
//    512-thread single-block-per-bucket gather slower than 2x256.
//  r10 counters: bin_scatter at 256 threads = 293 blocks = 1.14 blocks/CU
//    = ~12% occupancy ceiling, latency-bound -> 512 threads this round.

#define ROWS_PER_BUCKET 128
#define ROW_SHIFT 7
#define NBUCK_PAD 784        // 196*4, covers nbuck=782
#define SCAN_T 196
#define CAP 2048             // per-bucket fixed capacity
#define CHUNK 4096           // edges per bin_scatter block
#define SCT 512              // bin_scatter threads
#define EPT 8                // CHUNK / SCT edges per thread
#define MAXB 2048            // max bucket-chunk held in LDS by gather
#define COL_BITS 17
#define COL_MASK 0x1FFFF
#define OVF_CAP 65536

typedef __attribute__((ext_vector_type(8))) short bf16x8;
typedef __attribute__((ext_vector_type(4))) float f32x4;

__device__ __forceinline__ unsigned short f2bf(float x) {
    unsigned u = __float_as_uint(x);
    unsigned r = (u + 0x7FFFu + ((u >> 16) & 1u)) >> 16;   // RNE
    return (unsigned short)r;
}
__device__ __forceinline__ float bf2f(unsigned short h) {
    return __uint_as_float(((unsigned)h) << 16);
}

// MFMA node transform: block = 256 threads = 4 waves, 128 rows/block.
// Wave w: rows base+w*32 .. +31. Frags: A row = lane&15, k = 8*(lane>>4)+j;
// B col = lane&15, same k; D row = 4*(lane>>4)+i, col = lane&15.
// Also initializes gcursor/ovf_count (dead until bin_scatter launches).
__global__ __launch_bounds__(256) void node_transform(
    const float* __restrict__ X, const float* __restrict__ W1,
    const float* __restrict__ b1, const float* __restrict__ W2,
    const float* __restrict__ b2, unsigned short* __restrict__ Yb,
    float* __restrict__ Z, int n_nodes,
    int* __restrict__ gcursor, int* __restrict__ ovf_count)
{
    const int tid = threadIdx.x;

    // folded cursor_init
    if (gcursor) {
        int gi = blockIdx.x * 256 + tid;
        if (gi < NBUCK_PAD) gcursor[gi] = gi * CAP;
        if (gi == 0) *ovf_count = 0;
    }

    const int lane = tid & 63;
    const int wave = tid >> 6;          // 0..3
    const int lg = lane >> 4;           // 0..3
    const int lr = lane & 15;

    const int base = blockIdx.x * 128 + wave * 32;

    // ---- B fragments in registers: [mat][ks][cf] ----
    bf16x8 bw1[2][4];
    bf16x8 bw2[2][4];
#pragma unroll
    for (int ks = 0; ks < 2; ++ks) {
#pragma unroll
        for (int cf = 0; cf < 4; ++cf) {
            const int col = cf * 16 + lr;
            const int k0 = ks * 32 + lg * 8;
            bf16x8 t1, t2;
#pragma unroll
            for (int j = 0; j < 8; ++j) {
                t1[j] = (short)f2bf(W1[(k0 + j) * 64 + col]);
                t2[j] = (short)f2bf(W2[(k0 + j) * 64 + col]);
            }
            bw1[ks][cf] = t1;
            bw2[ks][cf] = t2;
        }
    }

    f32x4 acc1[2][4];
    f32x4 acc2[2][4];
#pragma unroll
    for (int rf = 0; rf < 2; ++rf)
#pragma unroll
        for (int cf = 0; cf < 4; ++cf) {
            acc1[rf][cf] = (f32x4){0.f, 0.f, 0.f, 0.f};
            acc2[rf][cf] = (f32x4){0.f, 0.f, 0.f, 0.f};
        }

    // ---- main: load A (X rows, coalesced 32B/lane), square, MFMA ----
#pragma unroll
    for (int rf = 0; rf < 2; ++rf) {
        const int row = base + rf * 16 + lr;
        const bool rok = row < n_nodes;
        const float* xp = X + (size_t)row * 64 + lg * 8;
#pragma unroll
        for (int ks = 0; ks < 2; ++ks) {
            float xv[8];
            if (rok) {
                float4 v0 = *(const float4*)(xp + ks * 32);
                float4 v1 = *(const float4*)(xp + ks * 32 + 4);
                xv[0] = v0.x; xv[1] = v0.y; xv[2] = v0.z; xv[3] = v0.w;
                xv[4] = v1.x; xv[5] = v1.y; xv[6] = v1.z; xv[7] = v1.w;
            } else {
#pragma unroll
                for (int j = 0; j < 8; ++j) xv[j] = 0.f;
            }
            bf16x8 a, q;
#pragma unroll
            for (int j = 0; j < 8; ++j) {
                a[j] = (short)f2bf(xv[j]);
                float s = xv[j] * xv[j];
                q[j] = (short)f2bf(s);
            }
#pragma unroll
            for (int cf = 0; cf < 4; ++cf) {
                acc1[rf][cf] = __builtin_amdgcn_mfma_f32_16x16x32_bf16(
                    a, bw1[ks][cf], acc1[rf][cf], 0, 0, 0);
                acc2[rf][cf] = __builtin_amdgcn_mfma_f32_16x16x32_bf16(
                    q, bw2[ks][cf], acc2[rf][cf], 0, 0, 0);
            }
        }
    }

    // ---- epilogue ----
    float bsv[4];
#pragma unroll
    for (int cf = 0; cf < 4; ++cf)
        bsv[cf] = b1[cf * 16 + lr] + b2[cf * 16 + lr];

#pragma unroll
    for (int rf = 0; rf < 2; ++rf) {
#pragma unroll
        for (int i = 0; i < 4; ++i) {
            const int row = base + rf * 16 + lg * 4 + i;
            if (row < n_nodes) {
#pragma unroll
                for (int cf = 0; cf < 4; ++cf) {
                    const float v1 = acc1[rf][cf][i];
                    const float y = v1 + acc2[rf][cf][i];
                    const float z = v1 + bsv[cf];
                    Yb[(size_t)row * 64 + cf * 16 + lr] = f2bf(y);
                    Z[(size_t)row * 64 + cf * 16 + lr] = z;
                }
            }
        }
    }
}

// ---------------- fixed-capacity bucket build ----------------

// LDS-staged binned scatter, single-atomic-pass (r7) at 512 threads:
//  pass 1: read each edge ONCE; the LDS histogram atomic's return value is
//          the in-bucket position; edge data stays in registers (EPT=8
//          statically-indexed -> VGPRs).
//  scan:   per-wave __shfl_up inclusive scan + 8-entry cross-wave fixup.
//  stage:  int2 LDS write at lstart[b]+p, no second atomic.
//  out:    i-ordered walk -> coalesced runs into packed[] per bucket.
__global__ __launch_bounds__(512) void bin_scatter(
    const int* __restrict__ rows, const int* __restrict__ cols,
    const float* __restrict__ vals, int* __restrict__ gcursor,
    int2* __restrict__ packed, int* __restrict__ ovf_count,
    int4* __restrict__ ovf, int n_edges) {
    __shared__ int lcount[NBUCK_PAD];              // 3.1 KB
    __shared__ int lstart[NBUCK_PAD];              // 3.1 KB
    __shared__ int gbase[NBUCK_PAD];               // 3.1 KB
    __shared__ int2 sxy[CHUNK];                    // 32 KB
    __shared__ unsigned short sbk[CHUNK];          // 8 KB
    __shared__ int wsum[8];

    int tid = threadIdx.x;
    int eb0 = blockIdx.x * CHUNK;
    int cnt = min(CHUNK, n_edges - eb0);

    for (int k = tid; k < NBUCK_PAD; k += SCT) lcount[k] = 0;
    __syncthreads();

    // pass 1: single read + histogram with position capture
    int eb_[EPT], ep_[EPT], ex_[EPT], ey_[EPT];
#pragma unroll
    for (int t = 0; t < EPT; ++t) {
        int i = tid + SCT * t;
        if (i < cnt) {
            int r = rows[eb0 + i];
            int b = r >> ROW_SHIFT;
            eb_[t] = b;
            ep_[t] = atomicAdd(&lcount[b], 1);
            ex_[t] = ((r & (ROWS_PER_BUCKET - 1)) << COL_BITS) | cols[eb0 + i];
            ey_[t] = __float_as_int(vals[eb0 + i]);
        } else {
            eb_[t] = -1; ep_[t] = 0; ex_[t] = 0; ey_[t] = 0;
        }
    }
    __syncthreads();

    // exclusive scan of lcount: thread t<SCAN_T owns buckets 4t..4t+3
    int c0 = 0, c1 = 0, c2 = 0, c3 = 0, psum = 0;
    if (tid < SCAN_T) {
        c0 = lcount[tid * 4 + 0]; c1 = lcount[tid * 4 + 1];
        c2 = lcount[tid * 4 + 2]; c3 = lcount[tid * 4 + 3];
        psum = c0 + c1 + c2 + c3;
    }
    const int lane = tid & 63;
    const int wv = tid >> 6;             // 0..7
    int incl = psum;
#pragma unroll
    for (int o = 1; o < 64; o <<= 1) {
        int n = __shfl_up(incl, o);
        if (lane >= o) incl += n;
    }
    if (lane == 63) wsum[wv] = incl;
    __syncthreads();
    int wpre = 0;
#pragma unroll
    for (int w = 0; w < 7; ++w)
        if (w < wv) wpre += wsum[w];
    int base0 = wpre + incl - psum;       // exclusive prefix of this thread
    if (tid < SCAN_T) {
        lstart[tid * 4 + 0] = base0;
        lstart[tid * 4 + 1] = base0 + c0;
        lstart[tid * 4 + 2] = base0 + c0 + c1;
        lstart[tid * 4 + 3] = base0 + c0 + c1 + c2;
    }
    __syncthreads();

    // reserve global space per bucket
    for (int k = tid; k < NBUCK_PAD; k += SCT) {
        if (lcount[k] > 0) gbase[k] = atomicAdd(&gcursor[k], lcount[k]);
    }

    // stage from registers (no atomics)
#pragma unroll
    for (int t = 0; t < EPT; ++t) {
        if (eb_[t] >= 0) {
            int p = lstart[eb_[t]] + ep_[t];
            sxy[p] = make_int2(ex_[t], ey_[t]);
            sbk[p] = (unsigned short)eb_[t];
        }
    }
    __syncthreads();

    // output: i-ordered -> per-bucket coalesced runs
    for (int i = tid; i < cnt; i += SCT) {
        int b = sbk[i];
        int2 a = sxy[i];
        int dest = gbase[b] + (i - lstart[b]);
        if (dest < (b + 1) * CAP) {
            packed[dest] = a;
        } else {
            int p = atomicAdd(ovf_count, 1);
            if (p < OVF_CAP)
                ovf[p] = make_int4(b * ROWS_PER_BUCKET + (a.x >> COL_BITS),
                                   a.x & COL_MASK, a.y, 0);
        }
    }
}

// 2 blocks per bucket (row halves, 64 rows each, all 64 features).
// In-LDS counting sort by local row (sorted int2 stored directly), then
// gather with 16-lane row-groups: each lane loads uint2 = 4 bf16 features,
// so one instruction fetches a full 128B Y row; 4 register accumulators per
// lane; float4 out RMW per row. 16 groups x 4 rows per block.
__global__ __launch_bounds__(256) void bucket_gather_quads(
    const int* __restrict__ gcursor, const int2* __restrict__ packed,
    const unsigned short* __restrict__ Yb, float* __restrict__ out,
    int n_nodes) {
    __shared__ int2 sxy[MAXB];                     // 16 KB, sorted by row
    __shared__ int hist[ROWS_PER_BUCKET];
    __shared__ int chs[ROWS_PER_BUCKET];
    __shared__ int chc[ROWS_PER_BUCKET];

    int tid = threadIdx.x;
    int bucket = blockIdx.x >> 1;
    int rhalf = (blockIdx.x & 1) * 64;   // which 64-row half this block owns
    int fquad = tid & 15;                // features 4*fquad .. 4*fquad+3
    int grp = tid >> 4;                  // 0..15 row-groups
    int s = bucket * CAP;
    int e = min(gcursor[bucket], s + CAP);
    int row0 = bucket * ROWS_PER_BUCKET;
    const uint2* __restrict__ Y64 = (const uint2*)Yb;   // row = 16 uint2

    for (int cb = s; cb < e; cb += MAXB) {
        int cnt = min(MAXB, e - cb);

        if (tid < ROWS_PER_BUCKET) hist[tid] = 0;
        __syncthreads();

        // pass 1: histogram of local rows
        for (int i = tid; i < cnt; i += 256)
            atomicAdd(&hist[packed[cb + i].x >> COL_BITS], 1);
        __syncthreads();

        if (tid < ROWS_PER_BUCKET) chs[tid] = hist[tid];
        __syncthreads();
#pragma unroll
        for (int o = 1; o < ROWS_PER_BUCKET; o <<= 1) {
            int t = 0;
            if (tid < ROWS_PER_BUCKET && tid >= o) t = chs[tid - o];
            __syncthreads();
            if (tid < ROWS_PER_BUCKET) chs[tid] += t;
            __syncthreads();
        }
        if (tid < ROWS_PER_BUCKET) {
            int excl = chs[tid] - hist[tid];
            chs[tid] = excl;
            chc[tid] = excl;
        }
        __syncthreads();

        // pass 2: scatter sorted edges directly into LDS (packed is L2-hot)
        for (int i = tid; i < cnt; i += 256) {
            int2 a = packed[cb + i];
            int p = atomicAdd(&chc[a.x >> COL_BITS], 1);
            sxy[p] = a;
        }
        __syncthreads();

        // gather: 16 groups x 4 rows; 16 lanes per row, 4 features/lane
        for (int rr = 0; rr < 4; ++rr) {
            int r = rhalf + grp * 4 + rr;
            int rc = hist[r];
            int node = row0 + r;
            if (rc == 0 || node >= n_nodes) continue;
            int rs = chs[r];
            float a0 = 0.f, a1 = 0.f, a2 = 0.f, a3 = 0.f;
            int j = 0;
            for (; j + 4 <= rc; j += 4) {
                int2 e0 = sxy[rs + j + 0], e1 = sxy[rs + j + 1];
                int2 e2 = sxy[rs + j + 2], e3 = sxy[rs + j + 3];
                uint2 u0 = Y64[(size_t)(e0.x & COL_MASK) * 16 + fquad];
                uint2 u1 = Y64[(size_t)(e1.x & COL_MASK) * 16 + fquad];
                uint2 u2 = Y64[(size_t)(e2.x & COL_MASK) * 16 + fquad];
                uint2 u3 = Y64[(size_t)(e3.x & COL_MASK) * 16 + fquad];
                float v0 = __int_as_float(e0.y), v1 = __int_as_float(e1.y);
                float v2 = __int_as_float(e2.y), v3 = __int_as_float(e3.y);
                a0 = fmaf(v0, __uint_as_float(u0.x << 16), a0);
                a1 = fmaf(v0, __uint_as_float(u0.x & 0xFFFF0000u), a1);
                a2 = fmaf(v0, __uint_as_float(u0.y << 16), a2);
                a3 = fmaf(v0, __uint_as_float(u0.y & 0xFFFF0000u), a3);
                a0 = fmaf(v1, __uint_as_float(u1.x << 16), a0);
                a1 = fmaf(v1, __uint_as_float(u1.x & 0xFFFF0000u), a1);
                a2 = fmaf(v1, __uint_as_float(u1.y << 16), a2);
                a3 = fmaf(v1, __uint_as_float(u1.y & 0xFFFF0000u), a3);
                a0 = fmaf(v2, __uint_as_float(u2.x << 16), a0);
                a1 = fmaf(v2, __uint_as_float(u2.x & 0xFFFF0000u), a1);
                a2 = fmaf(v2, __uint_as_float(u2.y << 16), a2);
                a3 = fmaf(v2, __uint_as_float(u2.y & 0xFFFF0000u), a3);
                a0 = fmaf(v3, __uint_as_float(u3.x << 16), a0);
                a1 = fmaf(v3, __uint_as_float(u3.x & 0xFFFF0000u), a1);
                a2 = fmaf(v3, __uint_as_float(u3.y << 16), a2);
                a3 = fmaf(v3, __uint_as_float(u3.y & 0xFFFF0000u), a3);
            }
            for (; j < rc; ++j) {
                int2 e0 = sxy[rs + j];
                uint2 u0 = Y64[(size_t)(e0.x & COL_MASK) * 16 + fquad];
                float v0 = __int_as_float(e0.y);
                a0 = fmaf(v0, __uint_as_float(u0.x << 16), a0);
                a1 = fmaf(v0, __uint_as_float(u0.x & 0xFFFF0000u), a1);
                a2 = fmaf(v0, __uint_as_float(u0.y << 16), a2);
                a3 = fmaf(v0, __uint_as_float(u0.y & 0xFFFF0000u), a3);
            }
            float4* op = (float4*)(out + (size_t)node * 64 + fquad * 4);
            float4 o = *op;
            o.x += a0; o.y += a1; o.z += a2; o.w += a3;
            *op = o;                                 // out holds Z
        }
        __syncthreads();
    }
}

// drains the (normally empty) overflow list with global atomics
__global__ __launch_bounds__(256) void overflow_scatter(
    const int* __restrict__ ovf_count, const int4* __restrict__ ovf,
    const unsigned short* __restrict__ Yb, float* __restrict__ out) {
    int cnt = min(*ovf_count, OVF_CAP);
    long long total = (long long)cnt * 64;
    for (long long i = blockIdx.x * 256 + threadIdx.x; i < total;
         i += (long long)gridDim.x * 256) {
        int e = (int)(i >> 6), f = (int)(i & 63);
        int4 a = ovf[e];
        atomicAdd(&out[(size_t)a.x * 64 + f],
                  __int_as_float(a.z) * bf2f(Yb[(size_t)a.y * 64 + f]));
    }
}

// ---------------- fallback (atomic path) ----------------

__global__ __launch_bounds__(256) void edge_scatter(
    const int* __restrict__ rows, const int* __restrict__ cols,
    const float* __restrict__ vals, const unsigned short* __restrict__ Yb,
    float* __restrict__ out, int n_edges)
{
    int t = blockIdx.x * 256 + threadIdx.x;
    int e = t >> 4;
    int f = (t & 15) << 2;
    if (e >= n_edges) return;
    int r = rows[e];
    int c = cols[e];
    float v = vals[e];
    const unsigned short* y = Yb + (size_t)c * 64 + f;
    float* o = out + (size_t)r * 64 + f;
    atomicAdd(o + 0, v * bf2f(y[0]));
    atomicAdd(o + 1, v * bf2f(y[1]));
    atomicAdd(o + 2, v * bf2f(y[2]));
    atomicAdd(o + 3, v * bf2f(y[3]));
}

extern "C" void kernel_launch(void* const* d_in, const int* in_sizes, int n_in,
                              void* d_out, int out_size, void* d_ws, size_t ws_size,
                              hipStream_t stream) {
    const int*   rows = (const int*)d_in[0];
    const int*   cols = (const int*)d_in[1];
    const float* vals = (const float*)d_in[2];
    const float* X    = (const float*)d_in[3];
    const float* W1   = (const float*)d_in[4];
    const float* b1   = (const float*)d_in[5];
    const float* W2   = (const float*)d_in[6];
    const float* b2   = (const float*)d_in[7];
    float* out = (float*)d_out;

    const int n_edges = in_sizes[0];
    const int n_nodes = in_sizes[3] / 64;
    const int nbuck = (n_nodes + ROWS_PER_BUCKET - 1) / ROWS_PER_BUCKET;

    char* ws = (char*)d_ws;
    size_t o_Yb     = 0;                                    // bf16 Y
    size_t o_packed = o_Yb + (size_t)n_nodes * 64 * 2;      // 16B-aligned (n*128)
    size_t o_ovf    = o_packed + (size_t)NBUCK_PAD * CAP * 8;
    size_t o_gcurs  = o_ovf + (size_t)OVF_CAP * 16;
    size_t o_ovfcnt = o_gcurs + NBUCK_PAD * 4;
    size_t need     = o_ovfcnt + 16;

    unsigned short* Yb = (unsigned short*)(ws + o_Yb);

    const bool fastpath =
        ws_size >= need && nbuck <= NBUCK_PAD && n_nodes <= (1 << COL_BITS);

    int2* packed  = (int2*)(ws + o_packed);
    int4* ovf     = (int4*)(ws + o_ovf);
    int*  gcursor = fastpath ? (int*)(ws + o_gcurs) : (int*)0;
    int*  ovfcnt  = (int*)(ws + o_ovfcnt);

    int nblocks = (n_nodes + 127) / 128;
    node_transform<<<nblocks, 256, 0, stream>>>(X, W1, b1, W2, b2, Yb, out,
                                                n_nodes, gcursor, ovfcnt);

    if (fastpath) {
        int eb = (n_edges + CHUNK - 1) / CHUNK;
        bin_scatter<<<eb, SCT, 0, stream>>>(rows, cols, vals, gcursor, packed,
                                            ovfcnt, ovf, n_edges);
        bucket_gather_quads<<<nbuck * 2, 256, 0, stream>>>(gcursor, packed, Yb,
                                                           out, n_nodes);
        overflow_scatter<<<128, 256, 0, stream>>>(ovfcnt, ovf, Yb, out);
    } else {
        long long threads = (long long)n_edges * 16;
        int eblocks = (int)((threads + 255) / 256);
        edge_scatter<<<eblocks, 256, 0, stream>>>(rows, cols, vals, Yb, out, n_edges);
    }
}